// Round 5
// baseline (117.964 us; speedup 1.0000x reference)
//
#include <hip/hip_runtime.h>
#include <math.h>

#define NUM_ENT 10000
#define NUM_REL 230
#define R2      460
#define S_DIM   96
#define T_DIM   32
#define DIM     128
#define N_NBR   32768
#define Q_ENT   4096
#define E_EDGE  32768
#define B_TRI   1024
#define BN_EPS  1e-5f
#define CHUNK   64
#define MAXB    (N_NBR / CHUNK + R2)   // 972 upper bound on matvec blocks

typedef __attribute__((ext_vector_type(8))) short bf16x8;
typedef __attribute__((ext_vector_type(4))) float f32x4;

// f32 -> bf16 round-to-nearest-even
__device__ __forceinline__ unsigned short f2bf(float f) {
    unsigned int u = __float_as_uint(f);
    u = (u + 0x7FFFu + ((u >> 16) & 1u)) >> 16;
    return (unsigned short)u;
}

// X LDS swizzle (ushort units): breaks the 256B row stride for A-frag b128
// reads. XOR bits >=3 keep 4-ushort groups contiguous (8B stores ok).
__device__ __forceinline__ int XIDX(int m, int d) {
    return (m * DIM + d) ^ ((m & 7) << 3);
}

// ---------------------------------------------------------------------------
// K00: zero the histogram/cursor ints (replaces the pathological 40us fill)
// ---------------------------------------------------------------------------
__global__ void k_zero(int* __restrict__ p, int n) {
    int i = blockIdx.x * blockDim.x + threadIdx.x;
    if (i < n) p[i] = 0;
}

// ---------------------------------------------------------------------------
// K0w: prepass: W[r] f32 -> bf16 in per-lane MFMA fragment order.
// Wfrag ushort offset for (r,kk,wv,h,lane,j):
//   ((r*4+kk)*4+wv)*1024 + h*512 + lane*8 + j
// value = bf16(W[r][32*kk + 8*(lane>>4) + j][32*wv + 16*h + (lane&15)])
// ---------------------------------------------------------------------------
__global__ __launch_bounds__(256, 2) void k_wfrag(const float* __restrict__ W,
                                                  unsigned short* __restrict__ Wfrag) {
    const int r = blockIdx.x;
    __shared__ float Wl[DIM * DIM];   // 64 KB
    const int t = threadIdx.x;
    {
        const float4* Wg = (const float4*)(W + (size_t)r * DIM * DIM);
        float4* Wl4 = (float4*)Wl;
        #pragma unroll
        for (int i = 0; i < 16; ++i)
            Wl4[t + i * 256] = Wg[t + i * 256];
    }
    __syncthreads();
    unsigned short* dst = Wfrag + (size_t)r * DIM * DIM;
    #pragma unroll
    for (int it = 0; it < 8; ++it) {
        const int id = t + it * 256;            // 0..2047
        const int lane = id & 63;
        const int h    = (id >> 6) & 1;
        const int wv   = (id >> 7) & 3;
        const int kk   = (id >> 9) & 3;
        const int n  = 32 * wv + 16 * h + (lane & 15);
        const int kb = 32 * kk + 8 * (lane >> 4);
        ushort4 lo, hi;
        lo.x = f2bf(Wl[(kb + 0) * DIM + n]);
        lo.y = f2bf(Wl[(kb + 1) * DIM + n]);
        lo.z = f2bf(Wl[(kb + 2) * DIM + n]);
        lo.w = f2bf(Wl[(kb + 3) * DIM + n]);
        hi.x = f2bf(Wl[(kb + 4) * DIM + n]);
        hi.y = f2bf(Wl[(kb + 5) * DIM + n]);
        hi.z = f2bf(Wl[(kb + 6) * DIM + n]);
        hi.w = f2bf(Wl[(kb + 7) * DIM + n]);
        *(ushort4*)&dst[id * 8]     = lo;
        *(ushort4*)&dst[id * 8 + 4] = hi;
    }
}

// ---------------------------------------------------------------------------
// K0a: fused histograms: rel_id -> 460 bins, pool_dst -> 4096 bins
// ---------------------------------------------------------------------------
__global__ void k_hist(const int* __restrict__ rel, const int* __restrict__ pdst,
                       int* __restrict__ hist_rel, int* __restrict__ hist_dst) {
    int i = blockIdx.x * blockDim.x + threadIdx.x;
    if (i < N_NBR) atomicAdd(&hist_rel[rel[i]], 1);
    if (i < E_EDGE) atomicAdd(&hist_dst[pdst[i]], 1);
}

// ---------------------------------------------------------------------------
// K0b: scan rel hist -> offsets[461]; scan ceil(cnt/CHUNK) -> blk_off[461];
// also emits block->relation map.
// ---------------------------------------------------------------------------
__global__ void k_scan_rel(const int* __restrict__ hist, int* __restrict__ offsets,
                           int* __restrict__ blk_off, int* __restrict__ map) {
    __shared__ int s[512];
    const int t = threadIdx.x;
    const int h = (t < R2) ? hist[t] : 0;
    s[t] = h;
    __syncthreads();
    for (int off = 1; off < 512; off <<= 1) {
        int a = (t >= off) ? s[t - off] : 0;
        __syncthreads();
        s[t] += a;
        __syncthreads();
    }
    if (t == 0) offsets[0] = 0;
    if (t < R2) offsets[t + 1] = s[t];
    __syncthreads();
    const int hb = (t < R2) ? (h + CHUNK - 1) / CHUNK : 0;
    s[t] = hb;
    __syncthreads();
    for (int off = 1; off < 512; off <<= 1) {
        int a = (t >= off) ? s[t - off] : 0;
        __syncthreads();
        s[t] += a;
        __syncthreads();
    }
    if (t == 0) blk_off[0] = 0;
    if (t < R2) {
        blk_off[t + 1] = s[t];
        const int ex = s[t] - hb;
        for (int b = 0; b < hb; ++b) map[ex + b] = t;
    }
}

// ---------------------------------------------------------------------------
// K0c: scan dst hist (4096 bins) -> dst_off[4097]. 1024 threads x 4 elems.
// ---------------------------------------------------------------------------
__global__ void k_scan_dst(const int* __restrict__ hist, int* __restrict__ offs) {
    __shared__ int s[1024];
    const int t = threadIdx.x;
    const int base = t * 4;
    int v0 = hist[base], v1 = hist[base + 1], v2 = hist[base + 2], v3 = hist[base + 3];
    s[t] = v0 + v1 + v2 + v3;
    __syncthreads();
    for (int off = 1; off < 1024; off <<= 1) {
        int a = (t >= off) ? s[t - off] : 0;
        __syncthreads();
        s[t] += a;
        __syncthreads();
    }
    int run = (t > 0) ? s[t - 1] : 0;
    offs[base] = run; run += v0;
    offs[base + 1] = run; run += v1;
    offs[base + 2] = run; run += v2;
    offs[base + 3] = run; run += v3;
    if (t == 1023) offs[4096] = run;
}

// ---------------------------------------------------------------------------
// K0d: scatter: rel-sorted neighbor order (+rank) and dst-sorted edge order
// ---------------------------------------------------------------------------
__global__ void k_scatter(const int* __restrict__ rel, const int* __restrict__ offsets,
                          int* __restrict__ cur_rel, int* __restrict__ order,
                          int* __restrict__ rank,
                          const int* __restrict__ pdst, const int* __restrict__ dst_off,
                          int* __restrict__ cur_dst, int* __restrict__ eorder) {
    int i = blockIdx.x * blockDim.x + threadIdx.x;
    if (i < N_NBR) {
        const int r = rel[i];
        const int pos = offsets[r] + atomicAdd(&cur_rel[r], 1);
        order[pos] = i;
        rank[i] = pos;
    }
    if (i < E_EDGE) {
        const int q = pdst[i];
        eorder[dst_off[q] + atomicAdd(&cur_dst[q], 1)] = i;
    }
}

// ---------------------------------------------------------------------------
// K1: MFMA matvec. One block = one 64-row chunk of one relation.
// X gathered as bf16 into swizzled LDS [64][128] (16 KB). No W LDS: B-frags
// read directly from fragment-ordered Wfrag (coalesced 16B/lane, L2-hot).
// 4 waves; wave wv owns output cols [32wv,32wv+32); acc[4 mtile][2 ntile].
// z written in SORTED row order (z_s).
// ---------------------------------------------------------------------------
__global__ __launch_bounds__(256, 4) void k_matvec(
    const int* __restrict__ map, const int* __restrict__ blk_off,
    const int* __restrict__ order, const int* __restrict__ offsets,
    const int* __restrict__ nbr,
    const float* __restrict__ years, const float* __restrict__ months, const float* __restrict__ days,
    const float* __restrict__ ent,
    const float* __restrict__ yf, const float* __restrict__ yp, const float* __restrict__ ya,
    const float* __restrict__ mf, const float* __restrict__ mp, const float* __restrict__ ma,
    const float* __restrict__ df, const float* __restrict__ dp, const float* __restrict__ da,
    const unsigned short* __restrict__ Wfrag, const float* __restrict__ bias,
    float* __restrict__ z_s)
{
    if (blockIdx.x >= blk_off[R2]) return;
    const int r     = map[blockIdx.x];
    const int chunk = blockIdx.x - blk_off[r];
    const int start = offsets[r];
    const int cnt   = offsets[r + 1] - start;
    const int cbase = chunk * CHUNK;
    const int mcnt  = min(CHUNK, cnt - cbase);

    __shared__ __align__(16) unsigned short Xl[CHUNK * DIM];  // 16 KB
    __shared__ int s_ord[CHUNK];
    __shared__ int s_ni[CHUNK];

    const int t = threadIdx.x;

    if (t < CHUNK) {
        int o = -1, ni = 0;
        if (t < mcnt) { o = order[start + cbase + t]; ni = nbr[o]; }
        s_ord[t] = o;
        s_ni[t]  = ni;
    }
    __syncthreads();

    // ---- gather X: 4 threads per row; entity 24 dims/thread, time 8/thread
    {
        const int m = t >> 2, s = t & 3;
        const int ni = s_ni[m];
        const bool vm = (m < mcnt);
        #pragma unroll
        for (int kk = 0; kk < 6; ++kk) {
            const int d = 4 * (s + 4 * kk);
            float4 e = *(const float4*)(ent + (size_t)ni * S_DIM + d);
            ushort4 b;
            b.x = vm ? f2bf(e.x) : 0; b.y = vm ? f2bf(e.y) : 0;
            b.z = vm ? f2bf(e.z) : 0; b.w = vm ? f2bf(e.w) : 0;
            *(ushort4*)&Xl[XIDX(m, d)] = b;
        }
        const int o = s_ord[m] < 0 ? 0 : s_ord[m];
        const float yr = years[o], mo = months[o], dy = days[o];
        #pragma unroll
        for (int hh = 0; hh < 2; ++hh) {
            const int j0 = s * 8 + hh * 4;
            const size_t tb = (size_t)ni * T_DIM + j0;
            const float4 vyf = *(const float4*)(yf + tb), vyp = *(const float4*)(yp + tb), vya = *(const float4*)(ya + tb);
            const float4 vmf = *(const float4*)(mf + tb), vmp = *(const float4*)(mp + tb), vma = *(const float4*)(ma + tb);
            const float4 vdf = *(const float4*)(df + tb), vdp = *(const float4*)(dp + tb), vda = *(const float4*)(da + tb);
            ushort4 b;
            #pragma unroll
            for (int j = 0; j < 4; ++j) {
                const float fy = ((const float*)&vyf)[j] * yr + ((const float*)&vyp)[j];
                const float fm = ((const float*)&vmf)[j] * mo + ((const float*)&vmp)[j];
                const float fd = ((const float*)&vdf)[j] * dy + ((const float*)&vdp)[j];
                float v = ((const float*)&vya)[j] * sinf(fy)
                        + ((const float*)&vma)[j] * sinf(fm)
                        + ((const float*)&vda)[j] * sinf(fd);
                ((unsigned short*)&b)[j] = vm ? f2bf(v) : 0;
            }
            *(ushort4*)&Xl[XIDX(m, S_DIM + j0)] = b;
        }
    }
    __syncthreads();

    // ---- MFMA
    const int wv = t >> 6;
    const int lane = t & 63;
    const int l15 = lane & 15;
    const int g = lane >> 4;

    f32x4 acc[4][2];
    #pragma unroll
    for (int i = 0; i < 4; ++i)
        #pragma unroll
        for (int j = 0; j < 2; ++j) acc[i][j] = (f32x4)0.f;

    const unsigned short* Wr = Wfrag + (size_t)r * DIM * DIM;

    #pragma unroll
    for (int kk = 0; kk < 4; ++kk) {
        const int k0 = kk * 32;
        bf16x8 a[4];
        #pragma unroll
        for (int mt = 0; mt < 4; ++mt)
            a[mt] = *(const bf16x8*)&Xl[XIDX(16 * mt + l15, k0 + 8 * g)];
        const bf16x8 b0 = *(const bf16x8*)&Wr[(size_t)((kk * 4 + wv) * 2 + 0) * 512 + lane * 8];
        const bf16x8 b1 = *(const bf16x8*)&Wr[(size_t)((kk * 4 + wv) * 2 + 1) * 512 + lane * 8];
        #pragma unroll
        for (int mt = 0; mt < 4; ++mt) {
            acc[mt][0] = __builtin_amdgcn_mfma_f32_16x16x32_bf16(a[mt], b0, acc[mt][0], 0, 0, 0);
            acc[mt][1] = __builtin_amdgcn_mfma_f32_16x16x32_bf16(a[mt], b1, acc[mt][1], 0, 0, 0);
        }
    }

    // ---- epilogue: bias + z_s store (sorted rows, contiguous)
    #pragma unroll
    for (int nt = 0; nt < 2; ++nt) {
        const int nn = 32 * wv + 16 * nt + l15;
        const float bv = bias[r * DIM + nn];
        #pragma unroll
        for (int mt = 0; mt < 4; ++mt) {
            #pragma unroll
            for (int reg = 0; reg < 4; ++reg) {
                const int ml = 16 * mt + 4 * g + reg;
                if (ml < mcnt)
                    z_s[(size_t)(start + cbase + ml) * DIM + nn] = acc[mt][nt][reg] + bv;
            }
        }
    }
}

// ---------------------------------------------------------------------------
// K2: BN stats from sorted z (contiguous per relation) -> affine scale/shift
// ---------------------------------------------------------------------------
__global__ void k_stats(const float* __restrict__ z_s, const int* __restrict__ offsets,
                        const float* __restrict__ gamma, const float* __restrict__ beta,
                        float* __restrict__ scale, float* __restrict__ shift)
{
    const int r = blockIdx.x;
    const int d = threadIdx.x;
    const int s0 = offsets[r], s1 = offsets[r + 1];
    float sum = 0.f, sq = 0.f;
    for (int i = s0; i < s1; ++i) {
        const float v = z_s[(size_t)i * DIM + d];
        sum += v; sq += v * v;
    }
    const int c = s1 - s0;
    const float denom = (float)max(c, 1);
    const float mean = sum / denom;
    const float var  = fmaxf(sq / denom - mean * mean, 0.0f);
    const int idx = r * DIM + d;
    float sc, sh;
    if (c > 1) {
        sc = gamma[idx] * rsqrtf(var + BN_EPS);
        sh = beta[idx] - mean * sc;
    } else {
        sc = 1.0f;
        sh = 0.0f;
    }
    scale[idx] = sc;
    shift[idx] = sh;
}

// ---------------------------------------------------------------------------
// K3: atomic-free pooling: one block per query, edges pre-sorted by dst.
// ---------------------------------------------------------------------------
__global__ void k_pool2(const int* __restrict__ eorder, const int* __restrict__ dst_off,
                        const int* __restrict__ pool_src, const int* __restrict__ rel,
                        const int* __restrict__ rank,
                        const float* __restrict__ z_s,
                        const float* __restrict__ scale, const float* __restrict__ shift,
                        float* __restrict__ emb)
{
    const int q = blockIdx.x;
    const int d = threadIdx.x;
    const int e0 = dst_off[q], e1 = dst_off[q + 1];
    float acc = 0.f;
    for (int e = e0; e < e1; ++e) {
        const int s = pool_src[eorder[e]];
        const int r = rel[s];
        const int p = rank[s];
        const float v = z_s[(size_t)p * DIM + d] * scale[r * DIM + d] + shift[r * DIM + d];
        acc += fmaxf(v, 0.f);
    }
    emb[(size_t)q * DIM + d] = (e1 > e0) ? acc / (float)(e1 - e0) : 0.f;
}

// ---------------------------------------------------------------------------
// K4: TransE scoring
// ---------------------------------------------------------------------------
__global__ void k_score(const int* __restrict__ head, const int* __restrict__ tail,
                        const int* __restrict__ rels,
                        const float* __restrict__ emb, const float* __restrict__ rel_embs,
                        float* __restrict__ out)
{
    const int b = blockIdx.x;
    const int d = threadIdx.x;
    const int h = head[b], tq = tail[b], r = rels[b];

    const float diff = emb[(size_t)h * DIM + d] + rel_embs[r * DIM + d]
                     - emb[(size_t)tq * DIM + d];
    float sq = diff * diff;
    for (int off = 32; off > 0; off >>= 1) sq += __shfl_down(sq, off);
    __shared__ float partial[2];
    if ((threadIdx.x & 63) == 0) partial[threadIdx.x >> 6] = sq;
    __syncthreads();
    if (threadIdx.x == 0) out[b] = -sqrtf(partial[0] + partial[1]);
}

// ---------------------------------------------------------------------------
extern "C" void kernel_launch(void* const* d_in, const int* in_sizes, int n_in,
                              void* d_out, int out_size, void* d_ws, size_t ws_size,
                              hipStream_t stream) {
    const int*   neighbor_idx = (const int*)  d_in[0];
    const int*   rel_id       = (const int*)  d_in[1];
    const float* years        = (const float*)d_in[2];
    const float* months       = (const float*)d_in[3];
    const float* days         = (const float*)d_in[4];
    const int*   pool_src     = (const int*)  d_in[5];
    const int*   pool_dst     = (const int*)  d_in[6];
    const int*   head_pos     = (const int*)  d_in[7];
    const int*   tail_pos     = (const int*)  d_in[8];
    const int*   rels         = (const int*)  d_in[9];
    const float* ent_embs     = (const float*)d_in[10];
    const float* y_freq       = (const float*)d_in[11];
    const float* y_phi        = (const float*)d_in[12];
    const float* y_amp        = (const float*)d_in[13];
    const float* m_freq       = (const float*)d_in[14];
    const float* m_phi        = (const float*)d_in[15];
    const float* m_amp        = (const float*)d_in[16];
    const float* d_freq       = (const float*)d_in[17];
    const float* d_phi        = (const float*)d_in[18];
    const float* d_amp        = (const float*)d_in[19];
    const float* rel_embs     = (const float*)d_in[20];
    const float* W            = (const float*)d_in[21];
    const float* bias         = (const float*)d_in[22];
    const float* gamma        = (const float*)d_in[23];
    const float* beta         = (const float*)d_in[24];

    float* out = (float*)d_out;

    // workspace layout (float units). 16B-aligned arrays first.
    float* ws = (float*)d_ws;
    size_t off = 0;
    unsigned short* Wfrag = (unsigned short*)(ws + off); off += (size_t)R2 * DIM * DIM / 2;  // 15 MB
    float* z_s   = ws + off; off += (size_t)N_NBR * DIM;   // 16 MB
    float* scale = ws + off; off += (size_t)R2 * DIM;
    float* shift = ws + off; off += (size_t)R2 * DIM;
    float* emb   = ws + off; off += (size_t)Q_ENT * DIM;
    int* hist_rel = (int*)(ws + off); off += R2;       // ---- zero region start
    int* hist_dst = (int*)(ws + off); off += Q_ENT;
    int* cur_rel  = (int*)(ws + off); off += R2;
    int* cur_dst  = (int*)(ws + off); off += Q_ENT;    // ---- zero region end
    int* offsets  = (int*)(ws + off); off += R2 + 1;
    int* blk_off  = (int*)(ws + off); off += R2 + 1;
    int* dst_off  = (int*)(ws + off); off += Q_ENT + 1;
    int* order    = (int*)(ws + off); off += N_NBR;
    int* rank     = (int*)(ws + off); off += N_NBR;
    int* eorder   = (int*)(ws + off); off += E_EDGE;
    int* map      = (int*)(ws + off); off += MAXB;

    const int nzero = 2 * (R2 + Q_ENT);   // 9112 ints
    k_zero<<<(nzero + 255) / 256, 256, 0, stream>>>(hist_rel, nzero);

    k_wfrag<<<R2, 256, 0, stream>>>(W, Wfrag);

    k_hist<<<(N_NBR + 255) / 256, 256, 0, stream>>>(rel_id, pool_dst, hist_rel, hist_dst);
    k_scan_rel<<<1, 512, 0, stream>>>(hist_rel, offsets, blk_off, map);
    k_scan_dst<<<1, 1024, 0, stream>>>(hist_dst, dst_off);
    k_scatter<<<(N_NBR + 255) / 256, 256, 0, stream>>>(rel_id, offsets, cur_rel, order, rank,
                                                       pool_dst, dst_off, cur_dst, eorder);

    k_matvec<<<MAXB, 256, 0, stream>>>(map, blk_off, order, offsets, neighbor_idx,
                                       years, months, days, ent_embs,
                                       y_freq, y_phi, y_amp,
                                       m_freq, m_phi, m_amp,
                                       d_freq, d_phi, d_amp,
                                       Wfrag, bias, z_s);

    k_stats<<<R2, DIM, 0, stream>>>(z_s, offsets, gamma, beta, scale, shift);

    k_pool2<<<Q_ENT, DIM, 0, stream>>>(eorder, dst_off, pool_src, rel_id, rank,
                                       z_s, scale, shift, emb);

    k_score<<<B_TRI, DIM, 0, stream>>>(head_pos, tail_pos, rels, emb, rel_embs, out);
}

// Round 6
// 87.184 us; speedup vs baseline: 1.3530x; 1.3530x over previous
//
#include <hip/hip_runtime.h>
#include <math.h>

#define NUM_ENT 10000
#define NUM_REL 230
#define R2      460
#define S_DIM   96
#define T_DIM   32
#define DIM     128
#define N_NBR   32768
#define Q_ENT   4096
#define E_EDGE  32768
#define B_TRI   1024
#define BN_EPS  1e-5f
#define CHUNK   64
#define MAXB    (N_NBR / CHUNK + R2)   // 972 upper bound on matvec blocks

typedef __attribute__((ext_vector_type(8))) short bf16x8;
typedef __attribute__((ext_vector_type(4))) float f32x4;

// f32 -> bf16 round-to-nearest-even
__device__ __forceinline__ unsigned short f2bf(float f) {
    unsigned int u = __float_as_uint(f);
    u = (u + 0x7FFFu + ((u >> 16) & 1u)) >> 16;
    return (unsigned short)u;
}

// X LDS swizzle (ushort units): breaks the 256B row stride for A-frag b128
// reads. XOR bits >=3 keep 4-ushort groups contiguous (8B stores ok).
__device__ __forceinline__ int XIDX(int m, int d) {
    return (m * DIM + d) ^ ((m & 7) << 3);
}

// ---------------------------------------------------------------------------
// K00: zero bn accumulators + histogram/cursor ints (int4 stores)
// ---------------------------------------------------------------------------
__global__ void k_zero(int* __restrict__ p, int n4) {
    int i = blockIdx.x * blockDim.x + threadIdx.x;
    if (i < n4) ((int4*)p)[i] = make_int4(0, 0, 0, 0);
}

// ---------------------------------------------------------------------------
// K0w: blocks [0,460): W[r] f32 -> bf16 in per-lane MFMA fragment order.
//      Wfrag ushort offset for (r,kk,wv,h,lane,j):
//        ((r*4+kk)*2*4 ... laid out as ((kk*4+wv)*2+h)*512 + lane*8 + j
//      value = bf16(W[r][32*kk + 8*(lane>>4) + j][32*wv + 16*h + (lane&15)])
//      blocks [460,588): fused histograms rel_id->460, pool_dst->4096
// ---------------------------------------------------------------------------
__global__ __launch_bounds__(256, 2) void k_wfrag_hist(
    const float* __restrict__ W, unsigned short* __restrict__ Wfrag,
    const int* __restrict__ rel, const int* __restrict__ pdst,
    int* __restrict__ hist_rel, int* __restrict__ hist_dst)
{
    const int t = threadIdx.x;
    if (blockIdx.x >= R2) {
        const int i = (blockIdx.x - R2) * 256 + t;
        if (i < N_NBR) atomicAdd(&hist_rel[rel[i]], 1);
        if (i < E_EDGE) atomicAdd(&hist_dst[pdst[i]], 1);
        return;
    }
    const int r = blockIdx.x;
    __shared__ float Wl[DIM * DIM];   // 64 KB
    {
        const float4* Wg = (const float4*)(W + (size_t)r * DIM * DIM);
        float4* Wl4 = (float4*)Wl;
        #pragma unroll
        for (int i = 0; i < 16; ++i)
            Wl4[t + i * 256] = Wg[t + i * 256];
    }
    __syncthreads();
    unsigned short* dst = Wfrag + (size_t)r * DIM * DIM;
    #pragma unroll
    for (int it = 0; it < 8; ++it) {
        const int id = t + it * 256;            // 0..2047
        const int lane = id & 63;
        const int h    = (id >> 6) & 1;
        const int wv   = (id >> 7) & 3;
        const int kk   = (id >> 9) & 3;
        const int n  = 32 * wv + 16 * h + (lane & 15);
        const int kb = 32 * kk + 8 * (lane >> 4);
        ushort4 lo, hi;
        lo.x = f2bf(Wl[(kb + 0) * DIM + n]);
        lo.y = f2bf(Wl[(kb + 1) * DIM + n]);
        lo.z = f2bf(Wl[(kb + 2) * DIM + n]);
        lo.w = f2bf(Wl[(kb + 3) * DIM + n]);
        hi.x = f2bf(Wl[(kb + 4) * DIM + n]);
        hi.y = f2bf(Wl[(kb + 5) * DIM + n]);
        hi.z = f2bf(Wl[(kb + 6) * DIM + n]);
        hi.w = f2bf(Wl[(kb + 7) * DIM + n]);
        *(ushort4*)&dst[id * 8]     = lo;
        *(ushort4*)&dst[id * 8 + 4] = hi;
    }
}

// ---------------------------------------------------------------------------
// K0b: fused scans (1024 threads). block 0: rel hist -> offsets[461] and
// ceil(cnt/CHUNK) -> blk_off[461] + block->rel map. block 1: dst hist
// (4096) -> dst_off[4097], 4 elems/thread.
// ---------------------------------------------------------------------------
__global__ void k_scan_both(const int* __restrict__ hist_rel, int* __restrict__ offsets,
                            int* __restrict__ blk_off, int* __restrict__ map,
                            const int* __restrict__ hist_dst, int* __restrict__ dst_off)
{
    __shared__ int s[1024];
    const int t = threadIdx.x;
    if (blockIdx.x == 0) {
        const int h = (t < R2) ? hist_rel[t] : 0;
        if (t < 512) s[t] = h;
        __syncthreads();
        for (int off = 1; off < 512; off <<= 1) {
            int a = (t >= off && t < 512) ? s[t - off] : 0;
            __syncthreads();
            if (t < 512) s[t] += a;
            __syncthreads();
        }
        if (t == 0) offsets[0] = 0;
        if (t < R2) offsets[t + 1] = s[t];
        __syncthreads();
        const int hb = (t < R2) ? (h + CHUNK - 1) / CHUNK : 0;
        if (t < 512) s[t] = hb;
        __syncthreads();
        for (int off = 1; off < 512; off <<= 1) {
            int a = (t >= off && t < 512) ? s[t - off] : 0;
            __syncthreads();
            if (t < 512) s[t] += a;
            __syncthreads();
        }
        if (t == 0) blk_off[0] = 0;
        if (t < R2) {
            blk_off[t + 1] = s[t];
            const int ex = s[t] - hb;
            for (int b = 0; b < hb; ++b) map[ex + b] = t;
        }
    } else {
        const int base = t * 4;
        int v0 = hist_dst[base], v1 = hist_dst[base + 1];
        int v2 = hist_dst[base + 2], v3 = hist_dst[base + 3];
        s[t] = v0 + v1 + v2 + v3;
        __syncthreads();
        for (int off = 1; off < 1024; off <<= 1) {
            int a = (t >= off) ? s[t - off] : 0;
            __syncthreads();
            s[t] += a;
            __syncthreads();
        }
        int run = (t > 0) ? s[t - 1] : 0;
        dst_off[base] = run; run += v0;
        dst_off[base + 1] = run; run += v1;
        dst_off[base + 2] = run; run += v2;
        dst_off[base + 3] = run; run += v3;
        if (t == 1023) dst_off[4096] = run;
    }
}

// ---------------------------------------------------------------------------
// K0d: scatter: rel-sorted neighbor order (+rank) and dst-sorted edge order
// ---------------------------------------------------------------------------
__global__ void k_scatter(const int* __restrict__ rel, const int* __restrict__ offsets,
                          int* __restrict__ cur_rel, int* __restrict__ order,
                          int* __restrict__ rank,
                          const int* __restrict__ pdst, const int* __restrict__ dst_off,
                          int* __restrict__ cur_dst, int* __restrict__ eorder) {
    int i = blockIdx.x * blockDim.x + threadIdx.x;
    if (i < N_NBR) {
        const int r = rel[i];
        const int pos = offsets[r] + atomicAdd(&cur_rel[r], 1);
        order[pos] = i;
        rank[i] = pos;
    }
    if (i < E_EDGE) {
        const int q = pdst[i];
        eorder[dst_off[q] + atomicAdd(&cur_dst[q], 1)] = i;
    }
}

// ---------------------------------------------------------------------------
// K1: MFMA matvec. One block = one 64-row chunk of one relation.
// X gathered as bf16 into swizzled LDS [64][128] (16 KB). B-frags read
// directly from fragment-ordered Wfrag (coalesced 16B/lane, L2-hot).
// 4 waves; wave wv owns output cols [32wv,32wv+32); acc[4 mtile][2 ntile].
// z written in SORTED row order (z_s). BN sums reduced in-wave (shfl over
// the g groups) and accumulated with per-column atomics (zeroed by k_zero).
// ---------------------------------------------------------------------------
__global__ __launch_bounds__(256, 4) void k_matvec(
    const int* __restrict__ map, const int* __restrict__ blk_off,
    const int* __restrict__ order, const int* __restrict__ offsets,
    const int* __restrict__ nbr,
    const float* __restrict__ years, const float* __restrict__ months, const float* __restrict__ days,
    const float* __restrict__ ent,
    const float* __restrict__ yf, const float* __restrict__ yp, const float* __restrict__ ya,
    const float* __restrict__ mf, const float* __restrict__ mp, const float* __restrict__ ma,
    const float* __restrict__ df, const float* __restrict__ dp, const float* __restrict__ da,
    const unsigned short* __restrict__ Wfrag, const float* __restrict__ bias,
    float* __restrict__ z_s, float* __restrict__ bn_sum, float* __restrict__ bn_sumsq)
{
    if (blockIdx.x >= blk_off[R2]) return;
    const int r     = map[blockIdx.x];
    const int chunk = blockIdx.x - blk_off[r];
    const int start = offsets[r];
    const int cnt   = offsets[r + 1] - start;
    const int cbase = chunk * CHUNK;
    const int mcnt  = min(CHUNK, cnt - cbase);

    __shared__ __align__(16) unsigned short Xl[CHUNK * DIM];  // 16 KB
    __shared__ int s_ord[CHUNK];
    __shared__ int s_ni[CHUNK];

    const int t = threadIdx.x;

    if (t < CHUNK) {
        int o = -1, ni = 0;
        if (t < mcnt) { o = order[start + cbase + t]; ni = nbr[o]; }
        s_ord[t] = o;
        s_ni[t]  = ni;
    }
    __syncthreads();

    // ---- gather X: 4 threads per row; entity 24 dims/thread, time 8/thread
    {
        const int m = t >> 2, s = t & 3;
        const int ni = s_ni[m];
        const bool vm = (m < mcnt);
        #pragma unroll
        for (int kk = 0; kk < 6; ++kk) {
            const int d = 4 * (s + 4 * kk);
            float4 e = *(const float4*)(ent + (size_t)ni * S_DIM + d);
            ushort4 b;
            b.x = vm ? f2bf(e.x) : 0; b.y = vm ? f2bf(e.y) : 0;
            b.z = vm ? f2bf(e.z) : 0; b.w = vm ? f2bf(e.w) : 0;
            *(ushort4*)&Xl[XIDX(m, d)] = b;
        }
        const int o = s_ord[m] < 0 ? 0 : s_ord[m];
        const float yr = years[o], mo = months[o], dy = days[o];
        #pragma unroll
        for (int hh = 0; hh < 2; ++hh) {
            const int j0 = s * 8 + hh * 4;
            const size_t tb = (size_t)ni * T_DIM + j0;
            const float4 vyf = *(const float4*)(yf + tb), vyp = *(const float4*)(yp + tb), vya = *(const float4*)(ya + tb);
            const float4 vmf = *(const float4*)(mf + tb), vmp = *(const float4*)(mp + tb), vma = *(const float4*)(ma + tb);
            const float4 vdf = *(const float4*)(df + tb), vdp = *(const float4*)(dp + tb), vda = *(const float4*)(da + tb);
            ushort4 b;
            #pragma unroll
            for (int j = 0; j < 4; ++j) {
                const float fy = ((const float*)&vyf)[j] * yr + ((const float*)&vyp)[j];
                const float fm = ((const float*)&vmf)[j] * mo + ((const float*)&vmp)[j];
                const float fd = ((const float*)&vdf)[j] * dy + ((const float*)&vdp)[j];
                float v = ((const float*)&vya)[j] * sinf(fy)
                        + ((const float*)&vma)[j] * sinf(fm)
                        + ((const float*)&vda)[j] * sinf(fd);
                ((unsigned short*)&b)[j] = vm ? f2bf(v) : 0;
            }
            *(ushort4*)&Xl[XIDX(m, S_DIM + j0)] = b;
        }
    }
    __syncthreads();

    // ---- MFMA
    const int wv = t >> 6;
    const int lane = t & 63;
    const int l15 = lane & 15;
    const int g = lane >> 4;

    f32x4 acc[4][2];
    #pragma unroll
    for (int i = 0; i < 4; ++i)
        #pragma unroll
        for (int j = 0; j < 2; ++j) acc[i][j] = (f32x4)0.f;

    const unsigned short* Wr = Wfrag + (size_t)r * DIM * DIM;

    #pragma unroll
    for (int kk = 0; kk < 4; ++kk) {
        const int k0 = kk * 32;
        bf16x8 a[4];
        #pragma unroll
        for (int mt = 0; mt < 4; ++mt)
            a[mt] = *(const bf16x8*)&Xl[XIDX(16 * mt + l15, k0 + 8 * g)];
        const bf16x8 b0 = *(const bf16x8*)&Wr[(size_t)((kk * 4 + wv) * 2 + 0) * 512 + lane * 8];
        const bf16x8 b1 = *(const bf16x8*)&Wr[(size_t)((kk * 4 + wv) * 2 + 1) * 512 + lane * 8];
        #pragma unroll
        for (int mt = 0; mt < 4; ++mt) {
            acc[mt][0] = __builtin_amdgcn_mfma_f32_16x16x32_bf16(a[mt], b0, acc[mt][0], 0, 0, 0);
            acc[mt][1] = __builtin_amdgcn_mfma_f32_16x16x32_bf16(a[mt], b1, acc[mt][1], 0, 0, 0);
        }
    }

    // ---- epilogue: bias + z_s store + BN column sums (shfl over g, atomics)
    #pragma unroll
    for (int nt = 0; nt < 2; ++nt) {
        const int nn = 32 * wv + 16 * nt + l15;
        const float bv = bias[r * DIM + nn];
        float lsum = 0.f, lsq = 0.f;
        #pragma unroll
        for (int mt = 0; mt < 4; ++mt) {
            #pragma unroll
            for (int reg = 0; reg < 4; ++reg) {
                const int ml = 16 * mt + 4 * g + reg;
                if (ml < mcnt) {
                    const float v = acc[mt][nt][reg] + bv;
                    z_s[(size_t)(start + cbase + ml) * DIM + nn] = v;
                    lsum += v;
                    lsq  += v * v;
                }
            }
        }
        lsum += __shfl_xor(lsum, 16); lsum += __shfl_xor(lsum, 32);
        lsq  += __shfl_xor(lsq, 16);  lsq  += __shfl_xor(lsq, 32);
        if (g == 0) {
            atomicAdd(&bn_sum[r * DIM + nn],   lsum);
            atomicAdd(&bn_sumsq[r * DIM + nn], lsq);
        }
    }
}

// ---------------------------------------------------------------------------
// K2: fold BN sums into affine scale/shift per (rel,dim). cnt<=1 -> identity.
// ---------------------------------------------------------------------------
__global__ void k_statsfold(const float* __restrict__ bn_sum, const float* __restrict__ bn_sumsq,
                            const int* __restrict__ hist,
                            const float* __restrict__ gamma, const float* __restrict__ beta,
                            float* __restrict__ scale, float* __restrict__ shift)
{
    const int r = blockIdx.x;
    const int d = threadIdx.x;
    const int i = r * DIM + d;
    const int c = hist[r];
    const float denom = (float)max(c, 1);
    const float mean = bn_sum[i] / denom;
    const float var  = fmaxf(bn_sumsq[i] / denom - mean * mean, 0.0f);
    float sc, sh;
    if (c > 1) {
        sc = gamma[i] * rsqrtf(var + BN_EPS);
        sh = beta[i] - mean * sc;
    } else {
        sc = 1.0f;
        sh = 0.0f;
    }
    scale[i] = sc;
    shift[i] = sh;
}

// ---------------------------------------------------------------------------
// K3: atomic-free pooling: one block per query, edges pre-sorted by dst.
// ---------------------------------------------------------------------------
__global__ void k_pool2(const int* __restrict__ eorder, const int* __restrict__ dst_off,
                        const int* __restrict__ pool_src, const int* __restrict__ rel,
                        const int* __restrict__ rank,
                        const float* __restrict__ z_s,
                        const float* __restrict__ scale, const float* __restrict__ shift,
                        float* __restrict__ emb)
{
    const int q = blockIdx.x;
    const int d = threadIdx.x;
    const int e0 = dst_off[q], e1 = dst_off[q + 1];
    float acc = 0.f;
    for (int e = e0; e < e1; ++e) {
        const int s = pool_src[eorder[e]];
        const int r = rel[s];
        const int p = rank[s];
        const float v = z_s[(size_t)p * DIM + d] * scale[r * DIM + d] + shift[r * DIM + d];
        acc += fmaxf(v, 0.f);
    }
    emb[(size_t)q * DIM + d] = (e1 > e0) ? acc / (float)(e1 - e0) : 0.f;
}

// ---------------------------------------------------------------------------
// K4: TransE scoring
// ---------------------------------------------------------------------------
__global__ void k_score(const int* __restrict__ head, const int* __restrict__ tail,
                        const int* __restrict__ rels,
                        const float* __restrict__ emb, const float* __restrict__ rel_embs,
                        float* __restrict__ out)
{
    const int b = blockIdx.x;
    const int d = threadIdx.x;
    const int h = head[b], tq = tail[b], r = rels[b];

    const float diff = emb[(size_t)h * DIM + d] + rel_embs[r * DIM + d]
                     - emb[(size_t)tq * DIM + d];
    float sq = diff * diff;
    for (int off = 32; off > 0; off >>= 1) sq += __shfl_down(sq, off);
    __shared__ float partial[2];
    if ((threadIdx.x & 63) == 0) partial[threadIdx.x >> 6] = sq;
    __syncthreads();
    if (threadIdx.x == 0) out[b] = -sqrtf(partial[0] + partial[1]);
}

// ---------------------------------------------------------------------------
extern "C" void kernel_launch(void* const* d_in, const int* in_sizes, int n_in,
                              void* d_out, int out_size, void* d_ws, size_t ws_size,
                              hipStream_t stream) {
    const int*   neighbor_idx = (const int*)  d_in[0];
    const int*   rel_id       = (const int*)  d_in[1];
    const float* years        = (const float*)d_in[2];
    const float* months       = (const float*)d_in[3];
    const float* days         = (const float*)d_in[4];
    const int*   pool_src     = (const int*)  d_in[5];
    const int*   pool_dst     = (const int*)  d_in[6];
    const int*   head_pos     = (const int*)  d_in[7];
    const int*   tail_pos     = (const int*)  d_in[8];
    const int*   rels         = (const int*)  d_in[9];
    const float* ent_embs     = (const float*)d_in[10];
    const float* y_freq       = (const float*)d_in[11];
    const float* y_phi        = (const float*)d_in[12];
    const float* y_amp        = (const float*)d_in[13];
    const float* m_freq       = (const float*)d_in[14];
    const float* m_phi        = (const float*)d_in[15];
    const float* m_amp        = (const float*)d_in[16];
    const float* d_freq       = (const float*)d_in[17];
    const float* d_phi        = (const float*)d_in[18];
    const float* d_amp        = (const float*)d_in[19];
    const float* rel_embs     = (const float*)d_in[20];
    const float* W            = (const float*)d_in[21];
    const float* bias         = (const float*)d_in[22];
    const float* gamma        = (const float*)d_in[23];
    const float* beta         = (const float*)d_in[24];

    float* out = (float*)d_out;

    // workspace layout (float units). 16B-aligned arrays first.
    // ZERO region must be contiguous: bn_sum, bn_sumsq, hist_rel, hist_dst,
    // cur_rel, cur_dst.
    float* ws = (float*)d_ws;
    size_t off = 0;
    unsigned short* Wfrag = (unsigned short*)(ws + off); off += (size_t)R2 * DIM * DIM / 2;  // 15 MB
    float* z_s   = ws + off; off += (size_t)N_NBR * DIM;   // 16 MB
    float* scale = ws + off; off += (size_t)R2 * DIM;
    float* shift = ws + off; off += (size_t)R2 * DIM;
    float* emb   = ws + off; off += (size_t)Q_ENT * DIM;
    float* bn_sum   = ws + off; off += (size_t)R2 * DIM;   // zero region start
    float* bn_sumsq = ws + off; off += (size_t)R2 * DIM;
    int* hist_rel = (int*)(ws + off); off += R2;
    int* hist_dst = (int*)(ws + off); off += Q_ENT;
    int* cur_rel  = (int*)(ws + off); off += R2;
    int* cur_dst  = (int*)(ws + off); off += Q_ENT;       // zero region end
    int* offsets  = (int*)(ws + off); off += R2 + 1;
    int* blk_off  = (int*)(ws + off); off += R2 + 1;
    int* dst_off  = (int*)(ws + off); off += Q_ENT + 1;
    int* order    = (int*)(ws + off); off += N_NBR;
    int* rank     = (int*)(ws + off); off += N_NBR;
    int* eorder   = (int*)(ws + off); off += E_EDGE;
    int* map      = (int*)(ws + off); off += MAXB;

    const int nzero  = 2 * R2 * DIM + 2 * (R2 + Q_ENT);   // 126,872 ints
    const int nzero4 = (nzero + 3) / 4;
    k_zero<<<(nzero4 + 255) / 256, 256, 0, stream>>>((int*)bn_sum, nzero4);

    k_wfrag_hist<<<R2 + (N_NBR + 255) / 256, 256, 0, stream>>>(
        W, Wfrag, rel_id, pool_dst, hist_rel, hist_dst);

    k_scan_both<<<2, 1024, 0, stream>>>(hist_rel, offsets, blk_off, map, hist_dst, dst_off);

    k_scatter<<<(N_NBR + 255) / 256, 256, 0, stream>>>(rel_id, offsets, cur_rel, order, rank,
                                                       pool_dst, dst_off, cur_dst, eorder);

    k_matvec<<<MAXB, 256, 0, stream>>>(map, blk_off, order, offsets, neighbor_idx,
                                       years, months, days, ent_embs,
                                       y_freq, y_phi, y_amp,
                                       m_freq, m_phi, m_amp,
                                       d_freq, d_phi, d_amp,
                                       Wfrag, bias, z_s, bn_sum, bn_sumsq);

    k_statsfold<<<R2, DIM, 0, stream>>>(bn_sum, bn_sumsq, hist_rel, gamma, beta, scale, shift);

    k_pool2<<<Q_ENT, DIM, 0, stream>>>(eorder, dst_off, pool_src, rel_id, rank,
                                       z_s, scale, shift, emb);

    k_score<<<B_TRI, DIM, 0, stream>>>(head_pos, tail_pos, rels, emb, rel_embs, out);
}